// Round 2
// baseline (1941.857 us; speedup 1.0000x reference)
//
#include <hip/hip_runtime.h>

// Problem constants
#define NATOMS 4096
#define NTYPES 2
#define NA 2048
#define MAXNB 100
#define JN 200          // neighbors per atom
#define TFD 4
#define E0 25           // emb hidden 0
#define E1 50           // emb hidden 1
#define GD 100          // GDIM
#define M2D 16
#define DD 1600         // D = M2*GDIM
#define FHD 240
#define INV200 (1.0f/200.0f)

// Output layout (floats): Etot@0 (1), Ei@1 (4096), F@4097 (12288), Virial@16385 (9)
#define OUT_EI 1
#define OUT_F 4097
#define OUT_V 16385

// Workspace layout (floats). Total = 13,547,520 floats = 54.2 MB
#define WS_DRQ 0L                 // 4096*1600  (dr, later overwritten by Q)
#define WS_XA 6553600L            // 4096*400
#define WS_P 8192000L             // 4096*400
#define WS_FH0 9830400L           // 4096*240
#define WS_FH1 10813440L          // 4096*240
#define WS_DH0G 11796480L         // 4096*240
#define WS_FW0T 12779520L         // 2*240*1600

// Small transposed weights in static device memory (filled by k_setup every launch).
// Accessed with wave-uniform indices inside kernels -> compiler emits s_load (SGPR
// operands for v_fmac), eliminating LDS traffic on the MLP inner loops.
__device__ float g_w1T[E1 * E0];   // [l][k] : w1T[l*25+k] = ew1[k*50+l]
__device__ float g_w2T[GD * E1];   // [g][l] : w2T[g*50+l] = ew2[l*100+g]
__device__ float g_c0[2 * E0];     // per-type layer0 constant

__device__ __forceinline__ float ftanh(float x) {
    float ax = fabsf(x);
    float e = __expf(-2.0f * ax);
    float t = (1.0f - e) / (1.0f + e);
    return copysignf(t, x);
}

// ---------------- setup: transpose fw0 + small weight transposes ----------------
__global__ void k_setup(const float* __restrict__ fw0, float* __restrict__ fw0T,
                        const float* __restrict__ ew0, const float* __restrict__ eb0,
                        const float* __restrict__ ew1, const float* __restrict__ ew2,
                        const float* __restrict__ tv) {
    int idx = blockIdx.x * 256 + threadIdx.x;
    if (idx < NTYPES * DD * FHD) {
        int t = idx / (DD * FHD);
        int r = idx % (DD * FHD);
        int o = r / DD, d = r % DD;
        fw0T[idx] = fw0[(long)t * DD * FHD + (long)d * FHD + o];
    }
    if (idx < GD * E1) {
        int g = idx / E1, l = idx % E1;
        g_w2T[idx] = ew2[l * GD + g];
    }
    if (idx < E1 * E0) {
        int l = idx / E0, k = idx % E0;
        g_w1T[idx] = ew1[k * E1 + l];
    }
    if (idx < 2 * E0) {
        int t = idx / E0, k = idx % E0;
        float c = eb0[k];
        for (int f = 0; f < TFD; ++f) c += tv[t * TFD + f] * ew0[(1 + f) * E0 + k];
        g_c0[idx] = c;
    }
}

// ---------------- K1: per-atom embedding forward -> xa -> dr (register MLP) ----------------
#define GCH 25
__global__ __launch_bounds__(256) void k1_emb(
    const float* __restrict__ Ri, const float* __restrict__ ew0,
    const float* __restrict__ eb1, const float* __restrict__ eb2,
    float* __restrict__ dr_ws, float* __restrict__ xa_ws)
{
    __shared__ float a4s[JN * 4];
    __shared__ float c0s[2 * E0];
    __shared__ float Gs[GCH * 201];
    __shared__ float xas[4 * GD];
    __shared__ float red[256];

    int tid = threadIdx.x;
    int n = blockIdx.x;

    if (tid < 2 * E0) c0s[tid] = g_c0[tid];
    float4 a = make_float4(0.f, 0.f, 0.f, 0.f);
    if (tid < JN) {
        a = ((const float4*)Ri)[(long)n * JN + tid];
        ((float4*)a4s)[tid] = a;
    }
    __syncthreads();

    float h1[E1];
    if (tid < JN) {
        int tau = tid / MAXNB;
        float s = a.x;
        float h0[E0];
#pragma unroll
        for (int k = 0; k < E0; ++k) h0[k] = ftanh(fmaf(s, ew0[k], c0s[tau * E0 + k]));
#pragma unroll
        for (int l = 0; l < E1; ++l) {
            float acc = eb1[l];
#pragma unroll
            for (int k = 0; k < E0; ++k) acc = fmaf(h0[k], g_w1T[l * E0 + k], acc);
            h1[l] = ftanh(acc);
        }
    }

    int gl_r = tid % GCH;
    int c_r = (tid / GCH) % 4;
    int jh_r = tid / 100;

    for (int cc = 0; cc < 4; ++cc) {
        int g0 = cc * GCH;
        if (tid < JN) {
            for (int gl = 0; gl < GCH; ++gl) {
                int g = g0 + gl;
                float acc = eb2[g];
#pragma unroll
                for (int l = 0; l < E1; ++l) acc = fmaf(h1[l], g_w2T[g * E1 + l], acc);
                Gs[gl * 201 + tid] = ftanh(acc);
            }
        }
        __syncthreads();
        float s_ = 0.f;
        if (tid < JN) {
            const float* grow = &Gs[gl_r * 201 + jh_r * 100];
            const float* arow = &a4s[jh_r * 400 + c_r];
            for (int jj = 0; jj < 100; ++jj)
                s_ = fmaf(arow[jj * 4], grow[jj], s_);
        }
        red[tid] = s_;
        __syncthreads();
        if (tid < 100) {
            int c = tid / GCH, gl = tid % GCH;
            xas[c * GD + g0 + gl] = (red[tid] + red[tid + 100]) * INV200;
        }
        __syncthreads();
    }

    for (int i = tid; i < 4 * GD; i += 256) xa_ws[(long)n * 400 + i] = xas[i];
    for (int i = tid; i < DD; i += 256) {
        int gg = i / M2D, m = i % M2D;
        float v = 0.f;
#pragma unroll
        for (int c = 0; c < 4; ++c) v = fmaf(xas[c * GD + gg], xas[c * GD + m], v);
        dr_ws[(long)n * DD + i] = v;
    }
}

// ---------------- generic tiled fp32 GEMM: C = act(A@B + bias), per-type batch z ----------------
__global__ __launch_bounds__(256) void gemm_kernel(
    const float* __restrict__ Ab, const float* __restrict__ Bb,
    const float* __restrict__ biasb, float* __restrict__ Cb,
    int M, int Nn, int K, long sA, long sB, long sBias, long sC, int do_tanh)
{
    int t = blockIdx.z;
    const float* A = Ab + (long)t * sA;
    const float* B = Bb + (long)t * sB;
    const float* bias = biasb ? (biasb + (long)t * sBias) : nullptr;
    float* C = Cb + (long)t * sC;

    __shared__ float As[16 * 64];
    __shared__ float Bs[16 * 64];

    int tid = threadIdx.x;
    int n0 = blockIdx.x * 64;
    int m0 = blockIdx.y * 64;
    int tx = tid % 16, ty = tid / 16;

    float acc[4][4];
#pragma unroll
    for (int i = 0; i < 4; ++i)
#pragma unroll
        for (int j = 0; j < 4; ++j) acc[i][j] = 0.f;

    int a_m = tid / 4;
    int a_k = (tid % 4) * 4;
    int b_k = tid / 16;
    int b_n = (tid % 16) * 4;

    for (int k0 = 0; k0 < K; k0 += 16) {
        float4 av = *(const float4*)&A[(long)(m0 + a_m) * K + k0 + a_k];
        float4 bv = make_float4(0.f, 0.f, 0.f, 0.f);
        if (n0 + b_n < Nn) bv = *(const float4*)&B[(long)(k0 + b_k) * Nn + n0 + b_n];
        __syncthreads();
        As[(a_k + 0) * 64 + a_m] = av.x;
        As[(a_k + 1) * 64 + a_m] = av.y;
        As[(a_k + 2) * 64 + a_m] = av.z;
        As[(a_k + 3) * 64 + a_m] = av.w;
        *(float4*)&Bs[b_k * 64 + b_n] = bv;
        __syncthreads();
#pragma unroll
        for (int k = 0; k < 16; ++k) {
            float4 a4v = *(const float4*)&As[k * 64 + ty * 4];
            float4 b4v = *(const float4*)&Bs[k * 64 + tx * 4];
            acc[0][0] = fmaf(a4v.x, b4v.x, acc[0][0]);
            acc[0][1] = fmaf(a4v.x, b4v.y, acc[0][1]);
            acc[0][2] = fmaf(a4v.x, b4v.z, acc[0][2]);
            acc[0][3] = fmaf(a4v.x, b4v.w, acc[0][3]);
            acc[1][0] = fmaf(a4v.y, b4v.x, acc[1][0]);
            acc[1][1] = fmaf(a4v.y, b4v.y, acc[1][1]);
            acc[1][2] = fmaf(a4v.y, b4v.z, acc[1][2]);
            acc[1][3] = fmaf(a4v.y, b4v.w, acc[1][3]);
            acc[2][0] = fmaf(a4v.z, b4v.x, acc[2][0]);
            acc[2][1] = fmaf(a4v.z, b4v.y, acc[2][1]);
            acc[2][2] = fmaf(a4v.z, b4v.z, acc[2][2]);
            acc[2][3] = fmaf(a4v.z, b4v.w, acc[2][3]);
            acc[3][0] = fmaf(a4v.w, b4v.x, acc[3][0]);
            acc[3][1] = fmaf(a4v.w, b4v.y, acc[3][1]);
            acc[3][2] = fmaf(a4v.w, b4v.z, acc[3][2]);
            acc[3][3] = fmaf(a4v.w, b4v.w, acc[3][3]);
        }
    }
#pragma unroll
    for (int i = 0; i < 4; ++i) {
        int mm = m0 + ty * 4 + i;
#pragma unroll
        for (int j = 0; j < 4; ++j) {
            int nn = n0 + tx * 4 + j;
            if (nn < Nn) {
                float v = acc[i][j];
                if (bias) v += bias[nn];
                if (do_tanh) v = ftanh(v);
                C[(long)mm * Nn + nn] = v;
            }
        }
    }
}

// ---------------- K3a: per-atom Ei + Etot + dh0g ----------------
__global__ __launch_bounds__(256) void k3a(
    const float* __restrict__ fh0, const float* __restrict__ fh1,
    const float* __restrict__ fw1, const float* __restrict__ fw2, const float* __restrict__ fb2,
    float* __restrict__ out, float* __restrict__ dh0g)
{
    int n = blockIdx.x;
    int t = n / NA;
    int tid = threadIdx.x;
    __shared__ float u1s[FHD];
    __shared__ float red[256];

    float p = 0.f;
    if (tid < FHD) {
        float h1v = fh1[(long)n * FHD + tid];
        float w2v = fw2[t * FHD + tid];
        p = h1v * w2v;
        u1s[tid] = w2v * (1.f - h1v * h1v);
    }
    red[tid] = p;
    __syncthreads();
    for (int off = 128; off > 0; off >>= 1) {
        if (tid < off) red[tid] += red[tid + off];
        __syncthreads();
    }
    if (tid == 0) {
        float e = red[0] + fb2[t];
        out[OUT_EI + n] = e;
        atomicAdd(out, e);
    }
    if (tid < FHD) {
        const float* w1row = fw1 + (long)t * FHD * FHD + (long)tid * FHD;
        float acc = 0.f;
        for (int o = 0; o < FHD; ++o) acc = fmaf(u1s[o], w1row[o], acc);
        float h0v = fh0[(long)n * FHD + tid];
        dh0g[(long)n * FHD + tid] = acc * (1.f - h0v * h0v);
    }
}

// ---------------- K3b: per-atom P[c,g] from Q and xa (INV200 folded in) ----------------
__global__ __launch_bounds__(256) void k3b(
    const float* __restrict__ Q, const float* __restrict__ xa, float* __restrict__ P)
{
    int n = blockIdx.x;
    int tid = threadIdx.x;
    __shared__ float qs[DD];
    __shared__ float xs[400];
    for (int i = tid; i < DD; i += 256) qs[i] = Q[(long)n * DD + i];
    for (int i = tid; i < 400; i += 256) xs[i] = xa[(long)n * 400 + i];
    __syncthreads();
    for (int i = tid; i < 400; i += 256) {
        int c = i / GD, g = i % GD;
        float acc = 0.f;
        for (int m = 0; m < M2D; ++m) acc = fmaf(qs[g * M2D + m], xs[c * GD + m], acc);
        if (g < M2D) {
            for (int g2 = 0; g2 < GD; ++g2) acc = fmaf(qs[g2 * M2D + g], xs[c * GD + g2], acc);
        }
        P[(long)n * 400 + i] = acc * INV200;
    }
}

// ---------------- K4: per-(atom,neighbor) backward, forces, virial ----------------
__global__ __launch_bounds__(256) void k4(
    const float* __restrict__ Ri, const float* __restrict__ dfeat,
    const float* __restrict__ ImageDR, const int* __restrict__ list_neigh,
    const float* __restrict__ ew0,
    const float* __restrict__ eb1, const float* __restrict__ eb2,
    const float* __restrict__ Pws, float* __restrict__ out)
{
    __shared__ float c0s[2 * E0];
    __shared__ float red[9 * 256];

    int tid = threadIdx.x;
    int n = blockIdx.x;
    const float* Pn = Pws + (long)n * 400;

    if (tid < 2 * E0) c0s[tid] = g_c0[tid];
    __syncthreads();

    float dEdx0 = 0.f, dEdx1 = 0.f, dEdx2 = 0.f;
    float v00 = 0.f, v01 = 0.f, v02 = 0.f, v11 = 0.f, v12 = 0.f, v22 = 0.f;
    float cv0 = 0.f, cv1 = 0.f, cv2 = 0.f;
    int scat = -1;

    if (tid < JN) {
        int j = tid;
        float4 a = ((const float4*)Ri)[(long)n * JN + j];
        float s = a.x;
        int tau = j / MAXNB;

        float h0[E0], h1[E1];
#pragma unroll
        for (int k = 0; k < E0; ++k) h0[k] = ftanh(fmaf(s, ew0[k], c0s[tau * E0 + k]));
#pragma unroll
        for (int l = 0; l < E1; ++l) {
            float acc = eb1[l];
#pragma unroll
            for (int k = 0; k < E0; ++k) acc = fmaf(h0[k], g_w1T[l * E0 + k], acc);
            h1[l] = ftanh(acc);
        }
        float dh1[E1];
#pragma unroll
        for (int l = 0; l < E1; ++l) dh1[l] = 0.f;
        float dEda0 = 0.f, dEda1 = 0.f, dEda2 = 0.f, dEda3 = 0.f;

        for (int g = 0; g < GD; ++g) {
            float acc = eb2[g];
#pragma unroll
            for (int l = 0; l < E1; ++l) acc = fmaf(h1[l], g_w2T[g * E1 + l], acc);
            float G = ftanh(acc);
            float p0 = Pn[g], p1 = Pn[GD + g], p2 = Pn[2 * GD + g], p3 = Pn[3 * GD + g];
            float dEdG = p0 * a.x + p1 * a.y + p2 * a.z + p3 * a.w;
            dEda0 = fmaf(p0, G, dEda0);
            dEda1 = fmaf(p1, G, dEda1);
            dEda2 = fmaf(p2, G, dEda2);
            dEda3 = fmaf(p3, G, dEda3);
            float u2 = dEdG * (1.f - G * G);
#pragma unroll
            for (int l = 0; l < E1; ++l) dh1[l] = fmaf(u2, g_w2T[g * E1 + l], dh1[l]);
        }
        float dh0[E0];
#pragma unroll
        for (int k = 0; k < E0; ++k) dh0[k] = 0.f;
#pragma unroll
        for (int l = 0; l < E1; ++l) {
            float u1 = dh1[l] * (1.f - h1[l] * h1[l]);
#pragma unroll
            for (int k = 0; k < E0; ++k) dh0[k] = fmaf(u1, g_w1T[l * E0 + k], dh0[k]);
        }
        float ds = 0.f;
#pragma unroll
        for (int k = 0; k < E0; ++k) ds = fmaf(dh0[k] * (1.f - h0[k] * h0[k]), ew0[k], ds);
        dEda0 += ds;

        const float* df = dfeat + (long)(n * JN + j) * 12;
        dEdx0 = dEda0 * df[0] + dEda1 * df[3] + dEda2 * df[6] + dEda3 * df[9];
        dEdx1 = dEda0 * df[1] + dEda1 * df[4] + dEda2 * df[7] + dEda3 * df[10];
        dEdx2 = dEda0 * df[2] + dEda1 * df[5] + dEda2 * df[8] + dEda3 * df[11];

        int ln = list_neigh[(long)n * JN + j];
        if (ln > 0) {
            cv0 = dEdx0; cv1 = dEdx1; cv2 = dEdx2;
            int ii = ln - 1;
            scat = ii < (NATOMS - 1) ? ii : (NATOMS - 1);
            const float* im = ImageDR + (long)(n * JN + j) * 3;
            v00 = im[0] * cv0; v01 = im[0] * cv1; v02 = im[0] * cv2;
            v11 = im[1] * cv1; v12 = im[1] * cv2; v22 = im[2] * cv2;
        }
    }

    if (scat >= 0) {
        atomicAdd(&out[OUT_F + scat * 3 + 0], cv0);
        atomicAdd(&out[OUT_F + scat * 3 + 1], cv1);
        atomicAdd(&out[OUT_F + scat * 3 + 2], cv2);
    }

    red[0 * 256 + tid] = dEdx0;
    red[1 * 256 + tid] = dEdx1;
    red[2 * 256 + tid] = dEdx2;
    red[3 * 256 + tid] = v00;
    red[4 * 256 + tid] = v01;
    red[5 * 256 + tid] = v02;
    red[6 * 256 + tid] = v11;
    red[7 * 256 + tid] = v12;
    red[8 * 256 + tid] = v22;
    __syncthreads();
    for (int off = 128; off > 0; off >>= 1) {
        if (tid < off) {
#pragma unroll
            for (int q = 0; q < 9; ++q) red[q * 256 + tid] += red[q * 256 + tid + off];
        }
        __syncthreads();
    }
    if (tid == 0) {
        atomicAdd(&out[OUT_F + n * 3 + 0], -red[0 * 256]);
        atomicAdd(&out[OUT_F + n * 3 + 1], -red[1 * 256]);
        atomicAdd(&out[OUT_F + n * 3 + 2], -red[2 * 256]);
        atomicAdd(&out[OUT_V + 0], red[3 * 256]);
        atomicAdd(&out[OUT_V + 1], red[4 * 256]);
        atomicAdd(&out[OUT_V + 2], red[5 * 256]);
        atomicAdd(&out[OUT_V + 3], red[4 * 256]);
        atomicAdd(&out[OUT_V + 4], red[6 * 256]);
        atomicAdd(&out[OUT_V + 5], red[7 * 256]);
        atomicAdd(&out[OUT_V + 6], red[5 * 256]);
        atomicAdd(&out[OUT_V + 7], red[7 * 256]);
        atomicAdd(&out[OUT_V + 8], red[8 * 256]);
    }
}

extern "C" void kernel_launch(void* const* d_in, const int* in_sizes, int n_in,
                              void* d_out, int out_size, void* d_ws, size_t ws_size,
                              hipStream_t stream) {
    const float* Ri = (const float*)d_in[0];
    const float* dfeat = (const float*)d_in[1];
    const float* ImageDR = (const float*)d_in[2];
    const float* tv = (const float*)d_in[3];
    const float* ew0 = (const float*)d_in[4];
    const float* eb0 = (const float*)d_in[5];
    const float* ew1 = (const float*)d_in[6];
    const float* eb1 = (const float*)d_in[7];
    const float* ew2 = (const float*)d_in[8];
    const float* eb2 = (const float*)d_in[9];
    const float* fw0 = (const float*)d_in[10];
    const float* fb0 = (const float*)d_in[11];
    const float* fw1 = (const float*)d_in[12];
    const float* fb1 = (const float*)d_in[13];
    const float* fw2 = (const float*)d_in[14];
    const float* fb2 = (const float*)d_in[15];
    const int* list_neigh = (const int*)d_in[16];

    float* out = (float*)d_out;
    float* ws = (float*)d_ws;
    float* drQ = ws + WS_DRQ;
    float* xa = ws + WS_XA;
    float* P = ws + WS_P;
    float* fh0 = ws + WS_FH0;
    float* fh1 = ws + WS_FH1;
    float* dh0g = ws + WS_DH0G;
    float* fw0T = ws + WS_FW0T;

    hipMemsetAsync(d_out, 0, (size_t)out_size * sizeof(float), stream);

    k_setup<<<(NTYPES * DD * FHD + 255) / 256, 256, 0, stream>>>(fw0, fw0T, ew0, eb0, ew1, ew2, tv);

    k1_emb<<<NATOMS, 256, 0, stream>>>(Ri, ew0, eb1, eb2, drQ, xa);

    // fit forward: fh0 = tanh(dr @ fw0 + fb0), fh1 = tanh(fh0 @ fw1 + fb1)
    gemm_kernel<<<dim3(4, 32, 2), 256, 0, stream>>>(drQ, fw0, fb0, fh0,
        2048, 240, 1600, 2048L * 1600, 1600L * 240, 240L, 2048L * 240, 1);
    gemm_kernel<<<dim3(4, 32, 2), 256, 0, stream>>>(fh0, fw1, fb1, fh1,
        2048, 240, 240, 2048L * 240, 240L * 240, 240L, 2048L * 240, 1);

    k3a<<<NATOMS, 256, 0, stream>>>(fh0, fh1, fw1, fw2, fb2, out, dh0g);

    // Q = dh0g @ fw0^T  (overwrites dr buffer)
    gemm_kernel<<<dim3(25, 32, 2), 256, 0, stream>>>(dh0g, fw0T, nullptr, drQ,
        2048, 1600, 240, 2048L * 240, 240L * 1600, 0L, 2048L * 1600, 0);

    k3b<<<NATOMS, 256, 0, stream>>>(drQ, xa, P);

    k4<<<NATOMS, 256, 0, stream>>>(Ri, dfeat, ImageDR, list_neigh,
        ew0, eb1, eb2, P, out);
}

// Round 3
// 834.855 us; speedup vs baseline: 2.3260x; 2.3260x over previous
//
#include <hip/hip_runtime.h>

// Problem constants
#define NATOMS 4096
#define NTYPES 2
#define NA 2048
#define MAXNB 100
#define JN 200          // neighbors per atom
#define TFD 4
#define E0 25           // emb hidden 0
#define E1 50           // emb hidden 1
#define GD 100          // GDIM
#define M2D 16
#define DD 1600         // D = M2*GDIM
#define FHD 240
#define INV200 (1.0f/200.0f)

// Output layout (floats): Etot@0 (1), Ei@1 (4096), F@4097 (12288), Virial@16385 (9)
#define OUT_EI 1
#define OUT_F 4097
#define OUT_V 16385

// Workspace layout (floats)
#define WS_DRQ 0L                 // 4096*1600  (dr, later overwritten by Q)
#define WS_XA 6553600L            // 4096*400
#define WS_P 8192000L             // 4096*400
#define WS_FH0 9830400L           // 4096*240
#define WS_FH1 10813440L          // 4096*240
#define WS_DH0G 11796480L         // 4096*240
#define WS_FW0T 12779520L         // 2*240*1600

// Small transposed weights in static device memory (filled by k_setup every launch).
// Accessed with wave-uniform indices -> compiler emits s_load (SGPR operands for
// v_fmac), eliminating LDS traffic on the MLP inner loops.
__device__ float g_w1T[E1 * E0];   // [l][k] : w1T[l*25+k] = ew1[k*50+l]
__device__ float g_w2T[GD * E1];   // [g][l] : w2T[g*50+l] = ew2[l*100+g]
__device__ float g_c0[2 * E0];     // per-type layer0 constant

__device__ __forceinline__ float ftanh(float x) {
    float ax = fabsf(x);
    float e = __expf(-2.0f * ax);
    float t = (1.0f - e) / (1.0f + e);
    return copysignf(t, x);
}

// ---------------- setup: transpose fw0 + small weight transposes ----------------
__global__ void k_setup(const float* __restrict__ fw0, float* __restrict__ fw0T,
                        const float* __restrict__ ew0, const float* __restrict__ eb0,
                        const float* __restrict__ ew1, const float* __restrict__ ew2,
                        const float* __restrict__ tv) {
    int idx = blockIdx.x * 256 + threadIdx.x;
    if (idx < NTYPES * DD * FHD) {
        int t = idx / (DD * FHD);
        int r = idx % (DD * FHD);
        int o = r / DD, d = r % DD;
        fw0T[idx] = fw0[(long)t * DD * FHD + (long)d * FHD + o];
    }
    if (idx < GD * E1) {
        int g = idx / E1, l = idx % E1;
        g_w2T[idx] = ew2[l * GD + g];
    }
    if (idx < E1 * E0) {
        int l = idx / E0, k = idx % E0;
        g_w1T[idx] = ew1[k * E1 + l];
    }
    if (idx < 2 * E0) {
        int t = idx / E0, k = idx % E0;
        float c = eb0[k];
        for (int f = 0; f < TFD; ++f) c += tv[t * TFD + f] * ew0[(1 + f) * E0 + k];
        g_c0[idx] = c;
    }
}

// ---------------- K1: per-atom embedding forward -> xa -> dr (register MLP) ----------------
#define GCH 25
__global__ __launch_bounds__(256) void k1_emb(
    const float* __restrict__ Ri, const float* __restrict__ ew0,
    const float* __restrict__ eb1, const float* __restrict__ eb2,
    float* __restrict__ dr_ws, float* __restrict__ xa_ws)
{
    __shared__ float a4s[JN * 4];
    __shared__ float c0s[2 * E0];
    __shared__ float Gs[GCH * 201];
    __shared__ float xas[4 * GD];
    __shared__ float red[256];

    int tid = threadIdx.x;
    int n = blockIdx.x;

    if (tid < 2 * E0) c0s[tid] = g_c0[tid];
    float4 a = make_float4(0.f, 0.f, 0.f, 0.f);
    if (tid < JN) {
        a = ((const float4*)Ri)[(long)n * JN + tid];
        ((float4*)a4s)[tid] = a;
    }
    __syncthreads();

    float h1[E1];
    if (tid < JN) {
        int tau = tid / MAXNB;
        float s = a.x;
        float h0[E0];
#pragma unroll
        for (int k = 0; k < E0; ++k) h0[k] = ftanh(fmaf(s, ew0[k], c0s[tau * E0 + k]));
#pragma unroll
        for (int l = 0; l < E1; ++l) {
            float acc = eb1[l];
#pragma unroll
            for (int k = 0; k < E0; ++k) acc = fmaf(h0[k], g_w1T[l * E0 + k], acc);
            h1[l] = ftanh(acc);
        }
    }

    int gl_r = tid % GCH;
    int c_r = (tid / GCH) % 4;
    int jh_r = tid / 100;

    for (int cc = 0; cc < 4; ++cc) {
        int g0 = cc * GCH;
        if (tid < JN) {
            for (int gl = 0; gl < GCH; ++gl) {
                int g = g0 + gl;
                float a0 = 0.f, a1 = 0.f;
#pragma unroll
                for (int l = 0; l < E1; l += 2) {
                    a0 = fmaf(h1[l], g_w2T[g * E1 + l], a0);
                    a1 = fmaf(h1[l + 1], g_w2T[g * E1 + l + 1], a1);
                }
                Gs[gl * 201 + tid] = ftanh(a0 + a1 + eb2[g]);
            }
        }
        __syncthreads();
        float s_ = 0.f;
        if (tid < JN) {
            const float* grow = &Gs[gl_r * 201 + jh_r * 100];
            const float* arow = &a4s[jh_r * 400 + c_r];
            for (int jj = 0; jj < 100; ++jj)
                s_ = fmaf(arow[jj * 4], grow[jj], s_);
        }
        red[tid] = s_;
        __syncthreads();
        if (tid < 100) {
            int c = tid / GCH, gl = tid % GCH;
            xas[c * GD + g0 + gl] = (red[tid] + red[tid + 100]) * INV200;
        }
        __syncthreads();
    }

    for (int i = tid; i < 4 * GD; i += 256) xa_ws[(long)n * 400 + i] = xas[i];
    for (int i = tid; i < DD; i += 256) {
        int gg = i / M2D, m = i % M2D;
        float v = 0.f;
#pragma unroll
        for (int c = 0; c < 4; ++c) v = fmaf(xas[c * GD + gg], xas[c * GD + m], v);
        dr_ws[(long)n * DD + i] = v;
    }
}

// ---------------- generic tiled fp32 GEMM: C = act(A@B + bias), per-type batch z ----------------
__global__ __launch_bounds__(256) void gemm_kernel(
    const float* __restrict__ Ab, const float* __restrict__ Bb,
    const float* __restrict__ biasb, float* __restrict__ Cb,
    int M, int Nn, int K, long sA, long sB, long sBias, long sC, int do_tanh)
{
    int t = blockIdx.z;
    const float* A = Ab + (long)t * sA;
    const float* B = Bb + (long)t * sB;
    const float* bias = biasb ? (biasb + (long)t * sBias) : nullptr;
    float* C = Cb + (long)t * sC;

    __shared__ float As[16 * 64];
    __shared__ float Bs[16 * 64];

    int tid = threadIdx.x;
    int n0 = blockIdx.x * 64;
    int m0 = blockIdx.y * 64;
    int tx = tid % 16, ty = tid / 16;

    float acc[4][4];
#pragma unroll
    for (int i = 0; i < 4; ++i)
#pragma unroll
        for (int j = 0; j < 4; ++j) acc[i][j] = 0.f;

    int a_m = tid / 4;
    int a_k = (tid % 4) * 4;
    int b_k = tid / 16;
    int b_n = (tid % 16) * 4;

    for (int k0 = 0; k0 < K; k0 += 16) {
        float4 av = *(const float4*)&A[(long)(m0 + a_m) * K + k0 + a_k];
        float4 bv = make_float4(0.f, 0.f, 0.f, 0.f);
        if (n0 + b_n < Nn) bv = *(const float4*)&B[(long)(k0 + b_k) * Nn + n0 + b_n];
        __syncthreads();
        As[(a_k + 0) * 64 + a_m] = av.x;
        As[(a_k + 1) * 64 + a_m] = av.y;
        As[(a_k + 2) * 64 + a_m] = av.z;
        As[(a_k + 3) * 64 + a_m] = av.w;
        *(float4*)&Bs[b_k * 64 + b_n] = bv;
        __syncthreads();
#pragma unroll
        for (int k = 0; k < 16; ++k) {
            float4 a4v = *(const float4*)&As[k * 64 + ty * 4];
            float4 b4v = *(const float4*)&Bs[k * 64 + tx * 4];
            acc[0][0] = fmaf(a4v.x, b4v.x, acc[0][0]);
            acc[0][1] = fmaf(a4v.x, b4v.y, acc[0][1]);
            acc[0][2] = fmaf(a4v.x, b4v.z, acc[0][2]);
            acc[0][3] = fmaf(a4v.x, b4v.w, acc[0][3]);
            acc[1][0] = fmaf(a4v.y, b4v.x, acc[1][0]);
            acc[1][1] = fmaf(a4v.y, b4v.y, acc[1][1]);
            acc[1][2] = fmaf(a4v.y, b4v.z, acc[1][2]);
            acc[1][3] = fmaf(a4v.y, b4v.w, acc[1][3]);
            acc[2][0] = fmaf(a4v.z, b4v.x, acc[2][0]);
            acc[2][1] = fmaf(a4v.z, b4v.y, acc[2][1]);
            acc[2][2] = fmaf(a4v.z, b4v.z, acc[2][2]);
            acc[2][3] = fmaf(a4v.z, b4v.w, acc[2][3]);
            acc[3][0] = fmaf(a4v.w, b4v.x, acc[3][0]);
            acc[3][1] = fmaf(a4v.w, b4v.y, acc[3][1]);
            acc[3][2] = fmaf(a4v.w, b4v.z, acc[3][2]);
            acc[3][3] = fmaf(a4v.w, b4v.w, acc[3][3]);
        }
    }
#pragma unroll
    for (int i = 0; i < 4; ++i) {
        int mm = m0 + ty * 4 + i;
#pragma unroll
        for (int j = 0; j < 4; ++j) {
            int nn = n0 + tx * 4 + j;
            if (nn < Nn) {
                float v = acc[i][j];
                if (bias) v += bias[nn];
                if (do_tanh) v = ftanh(v);
                C[(long)mm * Nn + nn] = v;
            }
        }
    }
}

// ---------------- K3a: per-atom Ei + Etot + dh0g ----------------
__global__ __launch_bounds__(256) void k3a(
    const float* __restrict__ fh0, const float* __restrict__ fh1,
    const float* __restrict__ fw1, const float* __restrict__ fw2, const float* __restrict__ fb2,
    float* __restrict__ out, float* __restrict__ dh0g)
{
    int n = blockIdx.x;
    int t = n / NA;
    int tid = threadIdx.x;
    __shared__ float u1s[FHD];
    __shared__ float red[256];

    float p = 0.f;
    if (tid < FHD) {
        float h1v = fh1[(long)n * FHD + tid];
        float w2v = fw2[t * FHD + tid];
        p = h1v * w2v;
        u1s[tid] = w2v * (1.f - h1v * h1v);
    }
    red[tid] = p;
    __syncthreads();
    for (int off = 128; off > 0; off >>= 1) {
        if (tid < off) red[tid] += red[tid + off];
        __syncthreads();
    }
    if (tid == 0) {
        float e = red[0] + fb2[t];
        out[OUT_EI + n] = e;
        atomicAdd(out, e);
    }
    if (tid < FHD) {
        const float* w1row = fw1 + (long)t * FHD * FHD + (long)tid * FHD;
        float acc = 0.f;
        for (int o = 0; o < FHD; ++o) acc = fmaf(u1s[o], w1row[o], acc);
        float h0v = fh0[(long)n * FHD + tid];
        dh0g[(long)n * FHD + tid] = acc * (1.f - h0v * h0v);
    }
}

// ---------------- K3b: per-atom P[c,g] from Q and xa (INV200 folded in) ----------------
__global__ __launch_bounds__(256) void k3b(
    const float* __restrict__ Q, const float* __restrict__ xa, float* __restrict__ P)
{
    int n = blockIdx.x;
    int tid = threadIdx.x;
    __shared__ float qs[DD];
    __shared__ float xs[400];
    for (int i = tid; i < DD; i += 256) qs[i] = Q[(long)n * DD + i];
    for (int i = tid; i < 400; i += 256) xs[i] = xa[(long)n * 400 + i];
    __syncthreads();
    for (int i = tid; i < 400; i += 256) {
        int c = i / GD, g = i % GD;
        float acc = 0.f;
        for (int m = 0; m < M2D; ++m) acc = fmaf(qs[g * M2D + m], xs[c * GD + m], acc);
        if (g < M2D) {
            for (int g2 = 0; g2 < GD; ++g2) acc = fmaf(qs[g2 * M2D + g], xs[c * GD + g2], acc);
        }
        P[(long)n * 400 + i] = acc * INV200;
    }
}

// ---------------- K4: per-(atom,neighbor) backward, forces, virial ----------------
// 8 atoms per block, 1600 items over 256 threads (89% lane-active).
// Register arrays reduced to h1[50]+dh1[50] (~120 live VGPRs, below 128 cliff):
// dh0 folded into ds via q = w1T.t0; h0 recomputed at the end instead of kept live.
#define AB 8
__global__ __launch_bounds__(256, 2) void k4(
    const float* __restrict__ Ri, const float* __restrict__ dfeat,
    const float* __restrict__ ImageDR, const int* __restrict__ list_neigh,
    const float* __restrict__ ew0,
    const float* __restrict__ eb1, const float* __restrict__ eb2,
    const float* __restrict__ Pws, float* __restrict__ out)
{
    __shared__ float Ps[AB * 400];
    __shared__ float c0s[2 * E0];
    __shared__ float facc[AB * 3];
    __shared__ float vacc[6];

    int tid = threadIdx.x;
    int blk = blockIdx.x;
    long base_item = (long)blk * (AB * JN);

    if (tid < 2 * E0) c0s[tid] = g_c0[tid];
    if (tid < AB * 3) facc[tid] = 0.f;
    if (tid < 6) vacc[tid] = 0.f;
    for (int i = tid; i < AB * 400; i += 256) Ps[i] = Pws[(long)blk * (AB * 400) + i];
    __syncthreads();

    float v00 = 0.f, v01 = 0.f, v02 = 0.f, v11 = 0.f, v12 = 0.f, v22 = 0.f;

    for (int it = 0; it < (AB * JN + 255) / 256; ++it) {
        int idx = it * 256 + tid;
        if (idx < AB * JN) {
            int nl = idx / JN;
            int j = idx - nl * JN;
            long item = base_item + idx;
            float4 a = ((const float4*)Ri)[item];
            float s = a.x;
            int tau = j / MAXNB;
            const float* Pn = Ps + nl * 400;

            // forward
            float h1[E1];
            {
                float h0[E0];
#pragma unroll
                for (int k = 0; k < E0; ++k) h0[k] = ftanh(fmaf(s, ew0[k], c0s[tau * E0 + k]));
#pragma unroll
                for (int l = 0; l < E1; ++l) {
                    float a0 = 0.f, a1 = 0.f;
#pragma unroll
                    for (int k = 0; k < E0 - 1; k += 2) {
                        a0 = fmaf(h0[k], g_w1T[l * E0 + k], a0);
                        a1 = fmaf(h0[k + 1], g_w1T[l * E0 + k + 1], a1);
                    }
                    a0 = fmaf(h0[E0 - 1], g_w1T[l * E0 + E0 - 1], a0);
                    h1[l] = ftanh(a0 + a1 + eb1[l]);
                }
            }

            float dh1[E1];
#pragma unroll
            for (int l = 0; l < E1; ++l) dh1[l] = 0.f;
            float dEda0 = 0.f, dEda1 = 0.f, dEda2 = 0.f, dEda3 = 0.f;

            for (int g = 0; g < GD; ++g) {
                float a0 = 0.f, a1 = 0.f, a2 = 0.f, a3 = 0.f;
#pragma unroll
                for (int l = 0; l < E1; l += 4) {
                    a0 = fmaf(h1[l], g_w2T[g * E1 + l], a0);
                    a1 = fmaf(h1[l + 1], g_w2T[g * E1 + l + 1], a1);
                    a2 = fmaf(h1[l + 2], g_w2T[g * E1 + l + 2], a2);
                    a3 = fmaf(h1[l + 3], g_w2T[g * E1 + l + 3], a3);
                }
                float G = ftanh((a0 + a1) + (a2 + a3) + eb2[g]);
                float p0 = Pn[g], p1 = Pn[GD + g], p2 = Pn[2 * GD + g], p3 = Pn[3 * GD + g];
                float dEdG = p0 * a.x + p1 * a.y + p2 * a.z + p3 * a.w;
                dEda0 = fmaf(p0, G, dEda0);
                dEda1 = fmaf(p1, G, dEda1);
                dEda2 = fmaf(p2, G, dEda2);
                dEda3 = fmaf(p3, G, dEda3);
                float u2 = dEdG * (1.f - G * G);
#pragma unroll
                for (int l = 0; l < E1; ++l) dh1[l] = fmaf(u2, g_w2T[g * E1 + l], dh1[l]);
            }

            // t0[k] = (1-h0^2)*w0[k], recomputed; ds = sum_l u1[l] * (w1T[l,:].t0)
            float t0[E0];
#pragma unroll
            for (int k = 0; k < E0; ++k) {
                float h = ftanh(fmaf(s, ew0[k], c0s[tau * E0 + k]));
                t0[k] = (1.f - h * h) * ew0[k];
            }
            float ds = 0.f;
#pragma unroll
            for (int l = 0; l < E1; ++l) {
                float u1 = dh1[l] * (1.f - h1[l] * h1[l]);
                float q0 = 0.f, q1 = 0.f;
#pragma unroll
                for (int k = 0; k < E0 - 1; k += 2) {
                    q0 = fmaf(g_w1T[l * E0 + k], t0[k], q0);
                    q1 = fmaf(g_w1T[l * E0 + k + 1], t0[k + 1], q1);
                }
                q0 = fmaf(g_w1T[l * E0 + E0 - 1], t0[E0 - 1], q0);
                ds = fmaf(u1, q0 + q1, ds);
            }
            dEda0 += ds;

            const float* df = dfeat + item * 12;
            float dEdx0 = dEda0 * df[0] + dEda1 * df[3] + dEda2 * df[6] + dEda3 * df[9];
            float dEdx1 = dEda0 * df[1] + dEda1 * df[4] + dEda2 * df[7] + dEda3 * df[10];
            float dEdx2 = dEda0 * df[2] + dEda1 * df[5] + dEda2 * df[8] + dEda3 * df[11];

            // center-atom force accumulation (all j)
            atomicAdd(&facc[nl * 3 + 0], dEdx0);
            atomicAdd(&facc[nl * 3 + 1], dEdx1);
            atomicAdd(&facc[nl * 3 + 2], dEdx2);

            int ln = list_neigh[item];
            if (ln > 0) {
                int ii = ln - 1;
                if (ii > NATOMS - 1) ii = NATOMS - 1;
                atomicAdd(&out[OUT_F + ii * 3 + 0], dEdx0);
                atomicAdd(&out[OUT_F + ii * 3 + 1], dEdx1);
                atomicAdd(&out[OUT_F + ii * 3 + 2], dEdx2);
                const float* im = ImageDR + item * 3;
                v00 = fmaf(im[0], dEdx0, v00);
                v01 = fmaf(im[0], dEdx1, v01);
                v02 = fmaf(im[0], dEdx2, v02);
                v11 = fmaf(im[1], dEdx1, v11);
                v12 = fmaf(im[1], dEdx2, v12);
                v22 = fmaf(im[2], dEdx2, v22);
            }
        }
    }

    // virial: wave shuffle reduce, wave leaders -> LDS
#pragma unroll
    for (int off = 32; off > 0; off >>= 1) {
        v00 += __shfl_down(v00, off);
        v01 += __shfl_down(v01, off);
        v02 += __shfl_down(v02, off);
        v11 += __shfl_down(v11, off);
        v12 += __shfl_down(v12, off);
        v22 += __shfl_down(v22, off);
    }
    if ((tid & 63) == 0) {
        atomicAdd(&vacc[0], v00);
        atomicAdd(&vacc[1], v01);
        atomicAdd(&vacc[2], v02);
        atomicAdd(&vacc[3], v11);
        atomicAdd(&vacc[4], v12);
        atomicAdd(&vacc[5], v22);
    }
    __syncthreads();
    if (tid < AB * 3) {
        int nl = tid / 3, c = tid % 3;
        atomicAdd(&out[OUT_F + (blk * AB + nl) * 3 + c], -facc[tid]);
    }
    if (tid < 9) {
        const int vmap[9] = {0, 1, 2, 1, 3, 4, 2, 4, 5};
        atomicAdd(&out[OUT_V + tid], vacc[vmap[tid]]);
    }
}

extern "C" void kernel_launch(void* const* d_in, const int* in_sizes, int n_in,
                              void* d_out, int out_size, void* d_ws, size_t ws_size,
                              hipStream_t stream) {
    const float* Ri = (const float*)d_in[0];
    const float* dfeat = (const float*)d_in[1];
    const float* ImageDR = (const float*)d_in[2];
    const float* tv = (const float*)d_in[3];
    const float* ew0 = (const float*)d_in[4];
    const float* eb0 = (const float*)d_in[5];
    const float* ew1 = (const float*)d_in[6];
    const float* eb1 = (const float*)d_in[7];
    const float* ew2 = (const float*)d_in[8];
    const float* eb2 = (const float*)d_in[9];
    const float* fw0 = (const float*)d_in[10];
    const float* fb0 = (const float*)d_in[11];
    const float* fw1 = (const float*)d_in[12];
    const float* fb1 = (const float*)d_in[13];
    const float* fw2 = (const float*)d_in[14];
    const float* fb2 = (const float*)d_in[15];
    const int* list_neigh = (const int*)d_in[16];

    float* out = (float*)d_out;
    float* ws = (float*)d_ws;
    float* drQ = ws + WS_DRQ;
    float* xa = ws + WS_XA;
    float* P = ws + WS_P;
    float* fh0 = ws + WS_FH0;
    float* fh1 = ws + WS_FH1;
    float* dh0g = ws + WS_DH0G;
    float* fw0T = ws + WS_FW0T;

    hipMemsetAsync(d_out, 0, (size_t)out_size * sizeof(float), stream);

    k_setup<<<(NTYPES * DD * FHD + 255) / 256, 256, 0, stream>>>(fw0, fw0T, ew0, eb0, ew1, ew2, tv);

    k1_emb<<<NATOMS, 256, 0, stream>>>(Ri, ew0, eb1, eb2, drQ, xa);

    // fit forward: fh0 = tanh(dr @ fw0 + fb0), fh1 = tanh(fh0 @ fw1 + fb1)
    gemm_kernel<<<dim3(4, 32, 2), 256, 0, stream>>>(drQ, fw0, fb0, fh0,
        2048, 240, 1600, 2048L * 1600, 1600L * 240, 240L, 2048L * 240, 1);
    gemm_kernel<<<dim3(4, 32, 2), 256, 0, stream>>>(fh0, fw1, fb1, fh1,
        2048, 240, 240, 2048L * 240, 240L * 240, 240L, 2048L * 240, 1);

    k3a<<<NATOMS, 256, 0, stream>>>(fh0, fh1, fw1, fw2, fb2, out, dh0g);

    // Q = dh0g @ fw0^T  (overwrites dr buffer)
    gemm_kernel<<<dim3(25, 32, 2), 256, 0, stream>>>(dh0g, fw0T, nullptr, drQ,
        2048, 1600, 240, 2048L * 240, 240L * 1600, 0L, 2048L * 1600, 0);

    k3b<<<NATOMS, 256, 0, stream>>>(drQ, xa, P);

    k4<<<NATOMS / AB, 256, 0, stream>>>(Ri, dfeat, ImageDR, list_neigh,
        ew0, eb1, eb2, P, out);
}